// Round 9
// baseline (91.659 us; speedup 1.0000x reference)
//
#include <hip/hip_runtime.h>

#define NUM_SEG 256
#define WAY 2
#define NCH 128
#define CHB 64                       // channels per block (ch-split)
#define HW 65536                     // 256*256
#define N_IMG 8
#define PIX_PER_BLK 2048
#define CHUNKS_PER_IMG 32
#define NTHREADS 512                 // 8 waves
#define TOTAL_SEG (N_IMG * NUM_SEG)  // 2048
#define NPART (N_IMG * CHUNKS_PER_IMG)     // 256 partial tiles
#define NBLOCKS (NPART * 2)          // 512 blocks, 2 per CU
#define PART_ELEMS (NUM_SEG * NCH)   // 32768
#define KW 32                        // pixels per K-chunk
#define NITER (PIX_PER_BLK / KW)     // 64
#define LDR 40                       // padded row, shorts (80 B, 16B-aligned)
#define SSTR 66                      // strip stride, floats (<=2-way banks)

typedef __attribute__((ext_vector_type(8))) short short8;
typedef __attribute__((ext_vector_type(4))) short short4v;
typedef __attribute__((ext_vector_type(4))) float f32x4;

static __device__ __forceinline__ unsigned short f2bf(float f) {
    unsigned int u = __float_as_uint(f);
    unsigned int r = u + 0x7FFFu + ((u >> 16) & 1u);
    return (unsigned short)(r >> 16);
}

static __device__ __forceinline__ short4v cvt4(float4 v) {
    short4v r;
    r[0] = (short)f2bf(v.x); r[1] = (short)f2bf(v.y);
    r[2] = (short)f2bf(v.z); r[3] = (short)f2bf(v.w);
    return r;
}

// One-hot MFMA segment-sum, round-8 control flow, 8-wave outer-product tiling.
// Block (n, chunk, h): C[ch in h*64..h*64+64)][seg] over 2048 px.
// Wave w: all 64 ch (4 A-frags) x seg[32w..32w+32) (2 B-frags) -> 6 reads / 8 MFMA.
__global__ __launch_bounds__(NTHREADS, 4)
void seg_mfma_kernel(const float* __restrict__ img,
                     const int* __restrict__ mask,
                     const int* __restrict__ segs,
                     float* __restrict__ ws_part,      // [NPART][256 seg][128 ch]
                     int* __restrict__ labcnt_g) {     // [TOTAL_SEG][WAY]
    __shared__ __align__(16) unsigned short OH[2][NUM_SEG][LDR]; // 40 KB one-hot B
    __shared__ __align__(16) unsigned short At[2][CHB][LDR];     // 10 KB bf16 A
    __shared__ unsigned char segb[PIX_PER_BLK];                  // 2 KB
    __shared__ int labc[NUM_SEG * WAY];                          // 2 KB
    // 54 KB -> 2 blocks/CU

    const int bid   = blockIdx.x;        // n*64 + chunk*2 + h
    const int h     = bid & 1;
    const int chunk = (bid >> 1) & 31;
    const int n     = bid >> 6;
    const int t     = threadIdx.x;
    const int lane  = t & 63;
    const int w     = t >> 6;            // wave 0..7 = seg group (32 segs)
    const int l15   = lane & 15;
    const int hi4   = lane >> 4;
    const int kA    = 8 * hi4;

    const long pixbase = (long)n * HW + chunk * PIX_PER_BLK;

    // zero OH (both buffers incl. pads) + labc
    {
        int4 z; z.x = z.y = z.z = z.w = 0;
        int4* p = (int4*)&OH[0][0][0];
        for (int i = t; i < (2 * NUM_SEG * LDR * 2) / 16; i += NTHREADS) p[i] = z;
        if (h == 0)
            for (int i = t; i < NUM_SEG * WAY; i += NTHREADS) labc[i] = 0;
    }
    __syncthreads();

    // stage seg ids (u8); h==0 blocks also build the label histogram
    for (int p = t; p < PIX_PER_BLK; p += NTHREADS) {
        int s = segs[pixbase + p];
        segb[p] = (unsigned char)s;
        if (h == 0) atomicAdd(&labc[s * 2 + mask[pixbase + p]], 1);
    }

    // A staging: 8 threads/row, float4 each (32 px/chunk, 128 B/row contiguous)
    const int arow = t >> 3;             // 0..63
    const int acol = (t & 7) * 4;        // 0..28
    const float* gA = img + (long)(n * NCH + h * CHB + arow) * HW
                          + chunk * PIX_PER_BLK + acol;

    // load chunk 0
    float4 fA = *(const float4*)(gA);
    __syncthreads();                      // segb + OH zeros visible

    // build chunk 0 into At[0], OH[0]
    *(short4v*)&At[0][arow][acol] = cvt4(fA);
    const bool sc = (t < KW);             // wave-0 lanes 0..31 own one-hot cols
    int s_prev = -1, s_cur = -1;
    if (sc) {
        s_cur = segb[t];
        OH[0][s_cur][t] = 0x3F80;         // bf16 1.0
    }
    fA = *(const float4*)(gA + KW);       // chunk 1 (to stage at it=0)
    float4 fB = *(const float4*)(gA + 2 * KW);   // chunk 2
    __syncthreads();                      // At[0], OH[0] visible

    f32x4 acc[4][2] = {};

    for (int it = 0; it < NITER; ++it) {
        const int cur = it & 1, nxt = cur ^ 1;

        // issue load for chunk it+3 (depth-3 prefetch)
        float4 fC = fB;
        if (it + 3 < NITER) fC = *(const float4*)(gA + (it + 3) * KW);
        int s_next = 0;
        if (sc && it + 1 < NITER) s_next = segb[(it + 1) * KW + t];

        // MFMA on chunk it: 4 A-frags x 2 B-frags
        short8 a0 = *(const short8*)&At[cur][      l15][kA];
        short8 a1 = *(const short8*)&At[cur][16  + l15][kA];
        short8 a2 = *(const short8*)&At[cur][32  + l15][kA];
        short8 a3 = *(const short8*)&At[cur][48  + l15][kA];
        #pragma unroll
        for (int nj = 0; nj < 2; ++nj) {
            short8 b = *(const short8*)&OH[cur][32 * w + 16 * nj + l15][kA];
            acc[0][nj] = __builtin_amdgcn_mfma_f32_16x16x32_bf16(a0, b, acc[0][nj], 0, 0, 0);
            acc[1][nj] = __builtin_amdgcn_mfma_f32_16x16x32_bf16(a1, b, acc[1][nj], 0, 0, 0);
            acc[2][nj] = __builtin_amdgcn_mfma_f32_16x16x32_bf16(a2, b, acc[2][nj], 0, 0, 0);
            acc[3][nj] = __builtin_amdgcn_mfma_f32_16x16x32_bf16(a3, b, acc[3][nj], 0, 0, 0);
        }

        // stage chunk it+1 into nxt buffers (disjoint from cur)
        if (it + 1 < NITER) {
            *(short4v*)&At[nxt][arow][acol] = cvt4(fA);
            if (sc) {
                if (s_prev >= 0 && s_prev != s_next) OH[nxt][s_prev][t] = 0;
                OH[nxt][s_next][t] = 0x3F80;
                s_prev = s_cur;
                s_cur  = s_next;
            }
        }
        __syncthreads();
        fA = fB; fB = fC;
    }

    // epilogue: strip [8 sg][16 seg][SSTR] fp32 (33.8 KB, reuse OH), 2 rounds
    float* strip = (float*)&OH[0][0][0];
    float* wsb = ws_part + (long)(n * CHUNKS_PER_IMG + chunk) * PART_ELEMS;
    #pragma unroll
    for (int nj = 0; nj < 2; ++nj) {
        // D layout: col(seg-local)=l15, row(ch-local)=4*hi4+r
        #pragma unroll
        for (int m = 0; m < 4; ++m)
            #pragma unroll
            for (int r = 0; r < 4; ++r)
                strip[(w * 16 + l15) * SSTR + 16 * m + 4 * hi4 + r] = acc[m][nj][r];
        __syncthreads();
        {   // copy 128 rows x 64 floats: 4 threads/row, 16 floats each
            const int row = t >> 2;          // sg = row>>4, sl = row&15
            const int off = (t & 3) * 16;
            const float* src = &strip[row * SSTR + off];
            const int sgid = 32 * (row >> 4) + 16 * nj + (row & 15);
            float* dst = wsb + (long)sgid * NCH + h * CHB + off;
            #pragma unroll
            for (int q = 0; q < 4; ++q) {
                float2 va = *(const float2*)(src + 4 * q);
                float2 vb = *(const float2*)(src + 4 * q + 2);
                float4 o; o.x = va.x; o.y = va.y; o.z = vb.x; o.w = vb.y;
                ((float4*)dst)[q] = o;
            }
        }
        __syncthreads();
    }

    if (h == 0)
        for (int i = t; i < NUM_SEG * WAY; i += NTHREADS)
            atomicAdd(&labcnt_g[n * NUM_SEG * WAY + i], labc[i]);
}

// sum 32 chunk-partials, divide by count, emit labels
__global__ void reduce_ws_kernel(const float* __restrict__ ws_part,
                                 const int* __restrict__ labcnt,
                                 float* __restrict__ out) {
    const int nmean = TOTAL_SEG * NCH;    // 262144
    int i = blockIdx.x * blockDim.x + threadIdx.x;
    if (i < nmean) {
        int nimg = i >> 15;               // / 32768
        int rem  = i & 32767;             // s*128 + c
        const float* base = ws_part + (long)nimg * 32 * PART_ELEMS + rem;
        float acc = 0.0f;
        #pragma unroll
        for (int j = 0; j < CHUNKS_PER_IMG; ++j)
            acc += base[(long)j * PART_ELEMS];
        int g  = i >> 7;                  // n*256 + s
        int c0 = labcnt[g * 2 + 0];
        int c1 = labcnt[g * 2 + 1];
        out[i] = acc / fmaxf((float)(c0 + c1), 1.0f);
    } else if (i < nmean + TOTAL_SEG) {
        int g = i - nmean;
        out[i] = (labcnt[g * 2 + 1] > labcnt[g * 2 + 0]) ? 1.0f : 0.0f;
    }
}

extern "C" void kernel_launch(void* const* d_in, const int* in_sizes, int n_in,
                              void* d_out, int out_size, void* d_ws, size_t ws_size,
                              hipStream_t stream) {
    const float* img  = (const float*)d_in[0];   // (8,128,256,256) f32
    const int*   mask = (const int*)d_in[1];     // (8,256,256) i32 in [0,2)
    const int*   segs = (const int*)d_in[2];     // (8,256,256) i32 in [0,256)

    float* out = (float*)d_out;

    const size_t part_bytes = (size_t)NPART * PART_ELEMS * sizeof(float); // 32 MB
    float* ws_part = (float*)d_ws;
    int*   labcnt  = (int*)((char*)d_ws + part_bytes);

    hipMemsetAsync(labcnt, 0, (size_t)TOTAL_SEG * WAY * sizeof(int), stream);

    seg_mfma_kernel<<<NBLOCKS, NTHREADS, 0, stream>>>(
        img, mask, segs, ws_part, labcnt);

    const int totalThreads = TOTAL_SEG * NCH + TOTAL_SEG;   // 264192
    reduce_ws_kernel<<<(totalThreads + 255) / 256, 256, 0, stream>>>(
        ws_part, labcnt, out);
}